// Round 12
// baseline (794.566 us; speedup 1.0000x reference)
//
#include <hip/hip_runtime.h>
#include <hip/hip_bf16.h>
#include <stdint.h>

#define B_ 4
#define S_ 128
#define CH 512

typedef __attribute__((ext_vector_type(8))) __bf16 bf16x8;
typedef __attribute__((ext_vector_type(4))) float  f32x4;
typedef __attribute__((ext_vector_type(16))) float f32x16;

__device__ __forceinline__ unsigned short f2b(float f) {
    union { float f; unsigned u; } v; v.f = f;
    unsigned r = v.u + 0x7FFFu + ((v.u >> 16) & 1u);
    return (unsigned short)(r >> 16);
}

#define GLD_LDS16(gp, lp) \
    __builtin_amdgcn_global_load_lds((const __attribute__((address_space(1))) void*)(gp), \
                                     (__attribute__((address_space(3))) void*)(lp), 16, 0, 0)

// ---------------- weights f32 -> bf16 ----------------
__global__ void cvt_w(const float* __restrict__ wq, const float* __restrict__ wp,
                      unsigned short* __restrict__ wqb, unsigned short* __restrict__ wpb) {
    int idx = (blockIdx.x * 256 + threadIdx.x) * 4;
    const float* s; unsigned short* d; int off;
    if (idx < 1536 * 512) { s = wq; d = wqb; off = idx; }
    else                  { s = wp; d = wpb; off = idx - 1536 * 512; }
    float4 v = *(const float4*)(s + off);
    ushort4 o; o.x = f2b(v.x); o.y = f2b(v.y); o.z = f2b(v.z); o.w = f2b(v.w);
    *(ushort4*)(d + off) = o;
}

// ------- x[b][c][h][w] f32 -> Xb[(b*128+w)*128+h][c] bf16 -------
__global__ __launch_bounds__(256) void k0_tr(const float* __restrict__ x,
                                             unsigned short* __restrict__ xb) {
    __shared__ unsigned short t[64][72];
    int bid = blockIdx.x;
    int ct = bid & 7, wt = (bid >> 3) & 1, h = (bid >> 4) & 127, b = bid >> 11;
    int tid = threadIdx.x;
    int c0 = ct * 64, w0 = wt * 64;
    const float* xp = x + ((size_t)b * CH * S_ + h) * S_;
    int wl = (tid & 15) * 4;
#pragma unroll
    for (int it = 0; it < 4; ++it) {
        int c = it * 16 + (tid >> 4);
        float4 v = *(const float4*)(xp + (size_t)(c0 + c) * (S_ * S_) + w0 + wl);
        t[wl + 0][c] = f2b(v.x);
        t[wl + 1][c] = f2b(v.y);
        t[wl + 2][c] = f2b(v.z);
        t[wl + 3][c] = f2b(v.w);
    }
    __syncthreads();
#pragma unroll
    for (int it = 0; it < 2; ++it) {
        int w = it * 32 + (tid >> 3);
        int ce = (tid & 7) * 8;
        int4 v = *(const int4*)&t[w][ce];
        size_t p = (size_t)((b * 128 + w0 + w) * 128 + h);
        *(int4*)(xb + p * 512 + c0 + ce) = v;
    }
}

// ===== 128x128 GEMM (32x32x16), 4 waves, BK=64, dbuf depth-1, 2 blocks/CU ====
// (r11 structure; r11's crash was a host-side launch-arg bug: EPI=2 launch
//  passed Mtiles=2 with a 4*512 grid -> nb up to 1023 >> 511 -> OOB. Fixed.)
//  - BK=64 -> LDS rows 128B (the measured 4.0 cy/read floor; r10's 64B rows
//    hit 12 cy/read). Linear layout, no swizzle (r1-r8: swizzles never beat it).
//  - 16 MFMA 32x32x16 per tile (516 cy/wave) amortize per-tile overhead.
// LDS 2 x (A 16KB | B 16KB) = 64KB -> 2 blocks/CU, 8 waves/CU in 2 INDEPENDENT
// barrier domains: when one block drains vmcnt(0)+barrier, the other computes
// (m97 mechanism). Per tile: stage j+1 at TOP (8 GLD/wave), 16 ds_read_b128,
// 16 MFMA, vmcnt(0), barrier. Overwrite safety: STAGE(buf^1, j+1) targets the
// buffer of tile j-1, dead since the end-of-(j-1) barrier.
template<int EPI>
__global__ __launch_bounds__(256, 2) void gemm8(
    const unsigned short* __restrict__ A,
    const unsigned short* __restrict__ Bm,
    unsigned short* __restrict__ outb,
    const float* __restrict__ xres,
    float* __restrict__ outf,
    int Mtiles)
{
    __shared__ unsigned short lds[32768];   // 2 x (A 8192 | B 8192) ushorts
    const int NT = 8;                       // 512 / BK(64)
    int nwg = gridDim.x;
    int wg = (blockIdx.x & 7) * (nwg >> 3) + (blockIdx.x >> 3);  // T1 XCD swizzle
    int mb = wg % Mtiles, nb = wg / Mtiles;
    int m0 = mb * 128, n0 = nb * 128;
    int tid = threadIdx.x, lane = tid & 63, wid = tid >> 6;
    int wm = wid >> 1, wn = wid & 1;

    f32x16 acc[2][2] = {};   // [mq][nq]

    // fragment reads (linear [row][k64] layout, 128B rows):
    // lane holds A[row=l31][k=ks*16+(l>>5)*8 ..+7]
    int l31 = lane & 31;
    int ck[4];
#pragma unroll
    for (int ks = 0; ks < 4; ++ks)
        ck[ks] = ks * 16 + (lane >> 5) * 8;
    int arow = (wm * 64 + l31) * 64;          // + mq*32*64
    int brow = 8192 + (wn * 64 + l31) * 64;   // + nq*32*64

    // staging: wave w covers rows 32w..32w+31 of A and B.
    // GLD dest = wave base + lane*16B -> row 8g+(l>>3), col (l&7)*8 (linear).
    const unsigned short* Asrc = A  + (size_t)(m0 + 32 * wid + (lane >> 3)) * 512 + (lane & 7) * 8;
    const unsigned short* Bsrc = Bm + (size_t)(n0 + 32 * wid + (lane >> 3)) * 512 + (lane & 7) * 8;

#define STAGE(buf, kt) do {                                                    \
        unsigned short* la_ = &lds[(buf) * 16384 + (32 * wid) * 64];           \
        unsigned short* lb_ = la_ + 8192;                                      \
        GLD_LDS16(Asrc + (kt) * 64,            la_);                           \
        GLD_LDS16(Asrc +  8 * 512 + (kt) * 64, la_ + 512);                     \
        GLD_LDS16(Asrc + 16 * 512 + (kt) * 64, la_ + 1024);                    \
        GLD_LDS16(Asrc + 24 * 512 + (kt) * 64, la_ + 1536);                    \
        GLD_LDS16(Bsrc + (kt) * 64,            lb_);                           \
        GLD_LDS16(Bsrc +  8 * 512 + (kt) * 64, lb_ + 512);                     \
        GLD_LDS16(Bsrc + 16 * 512 + (kt) * 64, lb_ + 1024);                    \
        GLD_LDS16(Bsrc + 24 * 512 + (kt) * 64, lb_ + 1536);                    \
    } while (0)

    // prologue: tile 0
    STAGE(0, 0);
    asm volatile("s_waitcnt vmcnt(0)" ::: "memory");
    __builtin_amdgcn_s_barrier();

    for (int j = 0; j < NT; ++j) {
        const int buf = j & 1;
        if (j + 1 < NT) STAGE(buf ^ 1, j + 1);     // issue early, drain late
        bf16x8 af[2][4], bq[2][4];
        {
            int ab = buf * 16384 + arow;
            int bb = buf * 16384 + brow;
#pragma unroll
            for (int mq = 0; mq < 2; ++mq)
#pragma unroll
                for (int ks = 0; ks < 4; ++ks)
                    af[mq][ks] = *(const bf16x8*)&lds[ab + mq * 2048 + ck[ks]];
#pragma unroll
            for (int nq = 0; nq < 2; ++nq)
#pragma unroll
                for (int ks = 0; ks < 4; ++ks)
                    bq[nq][ks] = *(const bf16x8*)&lds[bb + nq * 2048 + ck[ks]];
        }
        __builtin_amdgcn_s_setprio(1);
#pragma unroll
        for (int ks = 0; ks < 4; ++ks)
#pragma unroll
            for (int mq = 0; mq < 2; ++mq)
#pragma unroll
                for (int nq = 0; nq < 2; ++nq)
                    acc[mq][nq] = __builtin_amdgcn_mfma_f32_32x32x16_bf16(
                        af[mq][ks], bq[nq][ks], acc[mq][nq], 0, 0, 0);
        __builtin_amdgcn_s_setprio(0);
        if (j + 1 < NT) {
            asm volatile("s_waitcnt vmcnt(0)" ::: "memory");
            __builtin_amdgcn_s_barrier();
        }
    }
#undef STAGE

#pragma unroll
    for (int mq = 0; mq < 2; ++mq) {
#pragma unroll
        for (int qd = 0; qd < 4; ++qd) {
            int row0 = m0 + wm * 64 + mq * 32 + qd * 8 + ((lane >> 5) << 2);
#pragma unroll
            for (int nq = 0; nq < 2; ++nq) {
                int col = n0 + wn * 64 + nq * 32 + (lane & 31);
                int i = col & 127, sq = (col >> 7) & 127, bb = col >> 14;
                float a4[4];
#pragma unroll
                for (int r = 0; r < 4; ++r) a4[r] = acc[mq][nq][qd * 4 + r];
                if (EPI == 0) {
                    int g = row0 >> 6, d0 = row0 & 63;
                    if (g < 16) {
                        size_t base = ((size_t)(g * 4 + bb) * 16384 + (size_t)sq * 128 + i) * 64 + d0;
                        ushort4 o;
                        o.x = f2b(a4[0]); o.y = f2b(a4[1]); o.z = f2b(a4[2]); o.w = f2b(a4[3]);
                        *(ushort4*)(outb + base) = o;
                    } else {
                        size_t base = ((size_t)(g * 4 + bb) * 8192 + (size_t)sq * 64 + d0) * 128 + i;
                        outb[base]       = f2b(a4[0]);
                        outb[base + 128] = f2b(a4[1]);
                        outb[base + 256] = f2b(a4[2]);
                        outb[base + 384] = f2b(a4[3]);
                    }
                } else if (EPI == 1) {
                    size_t p2 = ((size_t)bb * 128 + i) * 128 + sq;
                    ushort4 o;
                    o.x = f2b(a4[0]); o.y = f2b(a4[1]); o.z = f2b(a4[2]); o.w = f2b(a4[3]);
                    *(ushort4*)(outb + p2 * 512 + row0) = o;
                } else {
                    size_t base = (((size_t)bb * 512 + row0) * 128 + sq) * 128 + i;
#pragma unroll
                    for (int r = 0; r < 4; ++r) {
                        size_t a_ = base + (size_t)r * 16384;
                        outf[a_] = xres[a_] + a4[r];
                    }
                }
            }
        }
    }
}

// ---------------- attention: one block per (b, seq, head) ----------------
__global__ __launch_bounds__(256) void attn_k(const unsigned short* __restrict__ qkv,
                                              unsigned short* __restrict__ o2) {
    __shared__ unsigned short Qs[128 * 80];
    __shared__ unsigned short Ks[128 * 80];
    __shared__ unsigned short Vt[64 * 144];
    int bid = blockIdx.x;
    int t = bid & 7, sq = (bid >> 3) & 127, b = bid >> 10;
    int tid = threadIdx.x, lane = tid & 63, wv = tid >> 6;
    const unsigned short* qg = qkv + ((size_t)(t * 4 + b) * 16384 + (size_t)sq * 128) * 64;
    const unsigned short* kg = qkv + ((size_t)((8 + t) * 4 + b) * 16384 + (size_t)sq * 128) * 64;
    const unsigned short* vg = qkv + ((size_t)((16 + t) * 4 + b) * 8192 + (size_t)sq * 64) * 128;
    {
        int r = tid >> 3, d0 = (tid & 7) * 8;
#pragma unroll
        for (int it = 0; it < 4; ++it) {
            *(int4*)(Qs + (it * 32 + r) * 80 + d0) = *(const int4*)(qg + (it * 32 + r) * 64 + d0);
            *(int4*)(Ks + (it * 32 + r) * 80 + d0) = *(const int4*)(kg + (it * 32 + r) * 64 + d0);
        }
        int r2 = tid >> 4, i0 = (tid & 15) * 8;
#pragma unroll
        for (int it = 0; it < 4; ++it)
            *(int4*)(Vt + (it * 16 + r2) * 144 + i0) = *(const int4*)(vg + (it * 16 + r2) * 128 + i0);
    }
    __syncthreads();

    f32x4 st[8][2] = {};
#pragma unroll
    for (int kk = 0; kk < 2; ++kk) {
        int ko = kk * 32 + (lane >> 4) * 8;
        bf16x8 bq[2];
#pragma unroll
        for (int nt = 0; nt < 2; ++nt)
            bq[nt] = *(const bf16x8*)(Qs + (wv * 32 + nt * 16 + (lane & 15)) * 80 + ko);
#pragma unroll
        for (int mt = 0; mt < 8; ++mt) {
            bf16x8 ak = *(const bf16x8*)(Ks + (mt * 16 + (lane & 15)) * 80 + ko);
#pragma unroll
            for (int nt = 0; nt < 2; ++nt)
                st[mt][nt] = __builtin_amdgcn_mfma_f32_16x16x32_bf16(ak, bq[nt], st[mt][nt], 0, 0, 0);
        }
    }

    const float sc = 0.125f * 1.44269504088896f;
    float mx[2], rinv[2];
    unsigned ppk[8][2][2];
#pragma unroll
    for (int nt = 0; nt < 2; ++nt) {
        float m = -3.0e38f;
#pragma unroll
        for (int mt = 0; mt < 8; ++mt)
#pragma unroll
            for (int r = 0; r < 4; ++r)
                m = fmaxf(m, st[mt][nt][r]);
        m = fmaxf(m, __shfl_xor(m, 16));
        m = fmaxf(m, __shfl_xor(m, 32));
        mx[nt] = m * sc;
    }
#pragma unroll
    for (int nt = 0; nt < 2; ++nt) {
        float s = 0.f;
#pragma unroll
        for (int mt = 0; mt < 8; ++mt) {
            float p0 = exp2f(st[mt][nt][0] * sc - mx[nt]);
            float p1 = exp2f(st[mt][nt][1] * sc - mx[nt]);
            float p2 = exp2f(st[mt][nt][2] * sc - mx[nt]);
            float p3 = exp2f(st[mt][nt][3] * sc - mx[nt]);
            s += (p0 + p1) + (p2 + p3);
            ppk[mt][nt][0] = (unsigned)f2b(p0) | ((unsigned)f2b(p1) << 16);
            ppk[mt][nt][1] = (unsigned)f2b(p2) | ((unsigned)f2b(p3) << 16);
        }
        s += __shfl_xor(s, 16);
        s += __shfl_xor(s, 32);
        rinv[nt] = 1.0f / s;
    }

    f32x4 ov[4][2] = {};
    int g = lane >> 4;
    int ls0 = (lane & 15) | ((g & 1) << 5);
    int ls1 = ls0 | 16;
    int hi = g >> 1;
#pragma unroll
    for (int kt = 0; kt < 4; ++kt) {
        bf16x8 bp[2];
#pragma unroll
        for (int nt = 0; nt < 2; ++nt) {
            unsigned a0 = (unsigned)__shfl((int)ppk[2 * kt    ][nt][0], ls0);
            unsigned b0 = (unsigned)__shfl((int)ppk[2 * kt + 1][nt][0], ls0);
            unsigned a1 = (unsigned)__shfl((int)ppk[2 * kt    ][nt][1], ls0);
            unsigned b1 = (unsigned)__shfl((int)ppk[2 * kt + 1][nt][1], ls0);
            unsigned a2 = (unsigned)__shfl((int)ppk[2 * kt    ][nt][0], ls1);
            unsigned b2 = (unsigned)__shfl((int)ppk[2 * kt + 1][nt][0], ls1);
            unsigned a3 = (unsigned)__shfl((int)ppk[2 * kt    ][nt][1], ls1);
            unsigned b3 = (unsigned)__shfl((int)ppk[2 * kt + 1][nt][1], ls1);
            union { unsigned u[4]; bf16x8 v; } pk;
            pk.u[0] = hi ? b0 : a0;
            pk.u[1] = hi ? b1 : a1;
            pk.u[2] = hi ? b2 : a2;
            pk.u[3] = hi ? b3 : a3;
            bp[nt] = pk.v;
        }
#pragma unroll
        for (int dt = 0; dt < 4; ++dt) {
            bf16x8 av = *(const bf16x8*)(Vt + (dt * 16 + (lane & 15)) * 144 + kt * 32 + (lane >> 4) * 8);
#pragma unroll
            for (int nt = 0; nt < 2; ++nt)
                ov[dt][nt] = __builtin_amdgcn_mfma_f32_16x16x32_bf16(av, bp[nt], ov[dt][nt], 0, 0, 0);
        }
    }

#pragma unroll
    for (int dt = 0; dt < 4; ++dt) {
        int d0 = dt * 16 + (lane >> 4) * 4;
#pragma unroll
        for (int nt = 0; nt < 2; ++nt) {
            int i = wv * 32 + nt * 16 + (lane & 15);
            size_t p = ((size_t)(b * 128 + sq)) * 128 + i;
            ushort4 o;
            o.x = f2b(ov[dt][nt][0] * rinv[nt]);
            o.y = f2b(ov[dt][nt][1] * rinv[nt]);
            o.z = f2b(ov[dt][nt][2] * rinv[nt]);
            o.w = f2b(ov[dt][nt][3] * rinv[nt]);
            *(ushort4*)(o2 + p * 512 + t * 64 + d0) = o;
        }
    }
}

extern "C" void kernel_launch(void* const* d_in, const int* in_sizes, int n_in,
                              void* d_out, int out_size, void* d_ws, size_t ws_size,
                              hipStream_t stream) {
    const float* x  = (const float*)d_in[0];
    const float* wq = (const float*)d_in[1];
    const float* wp = (const float*)d_in[2];
    float* out = (float*)d_out;
    char* ws = (char*)d_ws;
    unsigned short* wqb = (unsigned short*)(ws);
    unsigned short* wpb = (unsigned short*)(ws + ((size_t)2 << 20));
    unsigned short* xb  = (unsigned short*)(ws + ((size_t)4 << 20));
    unsigned short* o2  = (unsigned short*)(ws + ((size_t)68 << 20));
    unsigned short* qkv = (unsigned short*)(ws + ((size_t)132 << 20));

    cvt_w<<<1024, 256, 0, stream>>>(wq, wp, wqb, wpb);
    k0_tr<<<8192, 256, 0, stream>>>(x, xb);
    // pass 1 (axis = h)
    gemm8<0><<<12 * 512, 256, 0, stream>>>(wqb, xb, qkv, nullptr, nullptr, 12);
    attn_k<<<4096, 256, 0, stream>>>(qkv, o2);
    gemm8<1><<<4 * 512, 256, 0, stream>>>(wpb, o2, xb, nullptr, nullptr, 4);
    // pass 2 (axis = w)
    gemm8<0><<<12 * 512, 256, 0, stream>>>(wqb, xb, qkv, nullptr, nullptr, 12);
    attn_k<<<4096, 256, 0, stream>>>(qkv, o2);
    gemm8<2><<<4 * 512, 256, 0, stream>>>(wpb, o2, nullptr, x, out, 4);
}

// Round 13
// 598.419 us; speedup vs baseline: 1.3278x; 1.3278x over previous
//
#include <hip/hip_runtime.h>
#include <hip/hip_bf16.h>
#include <stdint.h>

#define B_ 4
#define S_ 128
#define CH 512

typedef __attribute__((ext_vector_type(8))) __bf16 bf16x8;
typedef __attribute__((ext_vector_type(4))) float  f32x4;
typedef __attribute__((ext_vector_type(16))) float f32x16;

__device__ __forceinline__ unsigned short f2b(float f) {
    union { float f; unsigned u; } v; v.f = f;
    unsigned r = v.u + 0x7FFFu + ((v.u >> 16) & 1u);
    return (unsigned short)(r >> 16);
}

#define GLD_LDS16(gp, lp) \
    __builtin_amdgcn_global_load_lds((const __attribute__((address_space(1))) void*)(gp), \
                                     (__attribute__((address_space(3))) void*)(lp), 16, 0, 0)

// ---------------- weights f32 -> bf16 ----------------
__global__ void cvt_w(const float* __restrict__ wq, const float* __restrict__ wp,
                      unsigned short* __restrict__ wqb, unsigned short* __restrict__ wpb) {
    int idx = (blockIdx.x * 256 + threadIdx.x) * 4;
    const float* s; unsigned short* d; int off;
    if (idx < 1536 * 512) { s = wq; d = wqb; off = idx; }
    else                  { s = wp; d = wpb; off = idx - 1536 * 512; }
    float4 v = *(const float4*)(s + off);
    ushort4 o; o.x = f2b(v.x); o.y = f2b(v.y); o.z = f2b(v.z); o.w = f2b(v.w);
    *(ushort4*)(d + off) = o;
}

// ------- x[b][c][h][w] f32 -> Xb[(b*128+w)*128+h][c] bf16 -------
__global__ __launch_bounds__(256) void k0_tr(const float* __restrict__ x,
                                             unsigned short* __restrict__ xb) {
    __shared__ unsigned short t[64][72];
    int bid = blockIdx.x;
    int ct = bid & 7, wt = (bid >> 3) & 1, h = (bid >> 4) & 127, b = bid >> 11;
    int tid = threadIdx.x;
    int c0 = ct * 64, w0 = wt * 64;
    const float* xp = x + ((size_t)b * CH * S_ + h) * S_;
    int wl = (tid & 15) * 4;
#pragma unroll
    for (int it = 0; it < 4; ++it) {
        int c = it * 16 + (tid >> 4);
        float4 v = *(const float4*)(xp + (size_t)(c0 + c) * (S_ * S_) + w0 + wl);
        t[wl + 0][c] = f2b(v.x);
        t[wl + 1][c] = f2b(v.y);
        t[wl + 2][c] = f2b(v.z);
        t[wl + 3][c] = f2b(v.w);
    }
    __syncthreads();
#pragma unroll
    for (int it = 0; it < 2; ++it) {
        int w = it * 32 + (tid >> 3);
        int ce = (tid & 7) * 8;
        int4 v = *(const int4*)&t[w][ce];
        size_t p = (size_t)((b * 128 + w0 + w) * 128 + h);
        *(int4*)(xb + p * 512 + c0 + ce) = v;
    }
}

// ===== 128x128 GEMM (32x32x16), 4 waves, BK=64, dbuf depth-1, 2 blocks/CU ====
// r12 + the r8-verified 3-bit XOR bank swizzle (r12's LINEAR 128B rows were the
// G4 catastrophic case: 28 cy/read, 8.8e7 conflicts; swizzled 128B rows measure
// 4.0 cy/read across r4-r8).
//   read swizzle:  ushort col ^= (row&7)<<3   (row = lane&31)
//   stage inverse: LDS dest linear (GLD constraint); global source col
//                  ((lane&7)^(lane>>3))*8 — staged rows are 8c+(lane>>3), so
//                  row&7 == lane>>3 for every chunk c. Exact involution pair.
// LDS 2 x (A 16KB | B 16KB) = 64KB -> 2 blocks/CU, 8 waves/CU in 2 INDEPENDENT
// barrier domains (one block's vmcnt(0)+barrier drain hidden by the other).
// Per tile: stage j+1 at TOP (8 GLD/wave), 16 ds_read_b128, 16 MFMA 32x32x16,
// vmcnt(0), barrier. STAGE(buf^1, j+1) targets tile j-1's buffer (dead).
template<int EPI>
__global__ __launch_bounds__(256, 2) void gemm8(
    const unsigned short* __restrict__ A,
    const unsigned short* __restrict__ Bm,
    unsigned short* __restrict__ outb,
    const float* __restrict__ xres,
    float* __restrict__ outf,
    int Mtiles)
{
    __shared__ unsigned short lds[32768];   // 2 x (A 8192 | B 8192) ushorts
    const int NT = 8;                       // 512 / BK(64)
    int nwg = gridDim.x;
    int wg = (blockIdx.x & 7) * (nwg >> 3) + (blockIdx.x >> 3);  // T1 XCD swizzle
    int mb = wg % Mtiles, nb = wg / Mtiles;
    int m0 = mb * 128, n0 = nb * 128;
    int tid = threadIdx.x, lane = tid & 63, wid = tid >> 6;
    int wm = wid >> 1, wn = wid & 1;

    f32x16 acc[2][2] = {};   // [mq][nq]

    // fragment reads: row=lane&31 (128B rows), col ushort ^= (row&7)<<3
    int l31 = lane & 31;
    int ck[4];
#pragma unroll
    for (int ks = 0; ks < 4; ++ks)
        ck[ks] = (ks * 16 + (lane >> 5) * 8) ^ ((lane & 7) << 3);
    int arow = (wm * 64 + l31) * 64;          // + mq*32*64
    int brow = 8192 + (wn * 64 + l31) * 64;   // + nq*32*64

    // staging: LDS dest linear (row 8c+(lane>>3), col (lane&7)*8);
    // global source col inverse-swizzled by row&7 = lane>>3
    int scol = ((lane & 7) ^ (lane >> 3)) * 8;
    const unsigned short* Asrc = A  + (size_t)(m0 + 32 * wid + (lane >> 3)) * 512 + scol;
    const unsigned short* Bsrc = Bm + (size_t)(n0 + 32 * wid + (lane >> 3)) * 512 + scol;

#define STAGE(buf, kt) do {                                                    \
        unsigned short* la_ = &lds[(buf) * 16384 + (32 * wid) * 64];           \
        unsigned short* lb_ = la_ + 8192;                                      \
        GLD_LDS16(Asrc + (kt) * 64,            la_);                           \
        GLD_LDS16(Asrc +  8 * 512 + (kt) * 64, la_ + 512);                     \
        GLD_LDS16(Asrc + 16 * 512 + (kt) * 64, la_ + 1024);                    \
        GLD_LDS16(Asrc + 24 * 512 + (kt) * 64, la_ + 1536);                    \
        GLD_LDS16(Bsrc + (kt) * 64,            lb_);                           \
        GLD_LDS16(Bsrc +  8 * 512 + (kt) * 64, lb_ + 512);                     \
        GLD_LDS16(Bsrc + 16 * 512 + (kt) * 64, lb_ + 1024);                    \
        GLD_LDS16(Bsrc + 24 * 512 + (kt) * 64, lb_ + 1536);                    \
    } while (0)

    // prologue: tile 0
    STAGE(0, 0);
    asm volatile("s_waitcnt vmcnt(0)" ::: "memory");
    __builtin_amdgcn_s_barrier();

    for (int j = 0; j < NT; ++j) {
        const int buf = j & 1;
        if (j + 1 < NT) STAGE(buf ^ 1, j + 1);     // issue early, drain late
        bf16x8 af[2][4], bq[2][4];
        {
            int ab = buf * 16384 + arow;
            int bb = buf * 16384 + brow;
#pragma unroll
            for (int mq = 0; mq < 2; ++mq)
#pragma unroll
                for (int ks = 0; ks < 4; ++ks)
                    af[mq][ks] = *(const bf16x8*)&lds[ab + mq * 2048 + ck[ks]];
#pragma unroll
            for (int nq = 0; nq < 2; ++nq)
#pragma unroll
                for (int ks = 0; ks < 4; ++ks)
                    bq[nq][ks] = *(const bf16x8*)&lds[bb + nq * 2048 + ck[ks]];
        }
        __builtin_amdgcn_s_setprio(1);
#pragma unroll
        for (int ks = 0; ks < 4; ++ks)
#pragma unroll
            for (int mq = 0; mq < 2; ++mq)
#pragma unroll
                for (int nq = 0; nq < 2; ++nq)
                    acc[mq][nq] = __builtin_amdgcn_mfma_f32_32x32x16_bf16(
                        af[mq][ks], bq[nq][ks], acc[mq][nq], 0, 0, 0);
        __builtin_amdgcn_s_setprio(0);
        if (j + 1 < NT) {
            asm volatile("s_waitcnt vmcnt(0)" ::: "memory");
            __builtin_amdgcn_s_barrier();
        }
    }
#undef STAGE

#pragma unroll
    for (int mq = 0; mq < 2; ++mq) {
#pragma unroll
        for (int qd = 0; qd < 4; ++qd) {
            int row0 = m0 + wm * 64 + mq * 32 + qd * 8 + ((lane >> 5) << 2);
#pragma unroll
            for (int nq = 0; nq < 2; ++nq) {
                int col = n0 + wn * 64 + nq * 32 + (lane & 31);
                int i = col & 127, sq = (col >> 7) & 127, bb = col >> 14;
                float a4[4];
#pragma unroll
                for (int r = 0; r < 4; ++r) a4[r] = acc[mq][nq][qd * 4 + r];
                if (EPI == 0) {
                    int g = row0 >> 6, d0 = row0 & 63;
                    if (g < 16) {
                        size_t base = ((size_t)(g * 4 + bb) * 16384 + (size_t)sq * 128 + i) * 64 + d0;
                        ushort4 o;
                        o.x = f2b(a4[0]); o.y = f2b(a4[1]); o.z = f2b(a4[2]); o.w = f2b(a4[3]);
                        *(ushort4*)(outb + base) = o;
                    } else {
                        size_t base = ((size_t)(g * 4 + bb) * 8192 + (size_t)sq * 64 + d0) * 128 + i;
                        outb[base]       = f2b(a4[0]);
                        outb[base + 128] = f2b(a4[1]);
                        outb[base + 256] = f2b(a4[2]);
                        outb[base + 384] = f2b(a4[3]);
                    }
                } else if (EPI == 1) {
                    size_t p2 = ((size_t)bb * 128 + i) * 128 + sq;
                    ushort4 o;
                    o.x = f2b(a4[0]); o.y = f2b(a4[1]); o.z = f2b(a4[2]); o.w = f2b(a4[3]);
                    *(ushort4*)(outb + p2 * 512 + row0) = o;
                } else {
                    size_t base = (((size_t)bb * 512 + row0) * 128 + sq) * 128 + i;
#pragma unroll
                    for (int r = 0; r < 4; ++r) {
                        size_t a_ = base + (size_t)r * 16384;
                        outf[a_] = xres[a_] + a4[r];
                    }
                }
            }
        }
    }
}

// ---------------- attention: one block per (b, seq, head) ----------------
__global__ __launch_bounds__(256) void attn_k(const unsigned short* __restrict__ qkv,
                                              unsigned short* __restrict__ o2) {
    __shared__ unsigned short Qs[128 * 80];
    __shared__ unsigned short Ks[128 * 80];
    __shared__ unsigned short Vt[64 * 144];
    int bid = blockIdx.x;
    int t = bid & 7, sq = (bid >> 3) & 127, b = bid >> 10;
    int tid = threadIdx.x, lane = tid & 63, wv = tid >> 6;
    const unsigned short* qg = qkv + ((size_t)(t * 4 + b) * 16384 + (size_t)sq * 128) * 64;
    const unsigned short* kg = qkv + ((size_t)((8 + t) * 4 + b) * 16384 + (size_t)sq * 128) * 64;
    const unsigned short* vg = qkv + ((size_t)((16 + t) * 4 + b) * 8192 + (size_t)sq * 64) * 128;
    {
        int r = tid >> 3, d0 = (tid & 7) * 8;
#pragma unroll
        for (int it = 0; it < 4; ++it) {
            *(int4*)(Qs + (it * 32 + r) * 80 + d0) = *(const int4*)(qg + (it * 32 + r) * 64 + d0);
            *(int4*)(Ks + (it * 32 + r) * 80 + d0) = *(const int4*)(kg + (it * 32 + r) * 64 + d0);
        }
        int r2 = tid >> 4, i0 = (tid & 15) * 8;
#pragma unroll
        for (int it = 0; it < 4; ++it)
            *(int4*)(Vt + (it * 16 + r2) * 144 + i0) = *(const int4*)(vg + (it * 16 + r2) * 128 + i0);
    }
    __syncthreads();

    f32x4 st[8][2] = {};
#pragma unroll
    for (int kk = 0; kk < 2; ++kk) {
        int ko = kk * 32 + (lane >> 4) * 8;
        bf16x8 bq[2];
#pragma unroll
        for (int nt = 0; nt < 2; ++nt)
            bq[nt] = *(const bf16x8*)(Qs + (wv * 32 + nt * 16 + (lane & 15)) * 80 + ko);
#pragma unroll
        for (int mt = 0; mt < 8; ++mt) {
            bf16x8 ak = *(const bf16x8*)(Ks + (mt * 16 + (lane & 15)) * 80 + ko);
#pragma unroll
            for (int nt = 0; nt < 2; ++nt)
                st[mt][nt] = __builtin_amdgcn_mfma_f32_16x16x32_bf16(ak, bq[nt], st[mt][nt], 0, 0, 0);
        }
    }

    const float sc = 0.125f * 1.44269504088896f;
    float mx[2], rinv[2];
    unsigned ppk[8][2][2];
#pragma unroll
    for (int nt = 0; nt < 2; ++nt) {
        float m = -3.0e38f;
#pragma unroll
        for (int mt = 0; mt < 8; ++mt)
#pragma unroll
            for (int r = 0; r < 4; ++r)
                m = fmaxf(m, st[mt][nt][r]);
        m = fmaxf(m, __shfl_xor(m, 16));
        m = fmaxf(m, __shfl_xor(m, 32));
        mx[nt] = m * sc;
    }
#pragma unroll
    for (int nt = 0; nt < 2; ++nt) {
        float s = 0.f;
#pragma unroll
        for (int mt = 0; mt < 8; ++mt) {
            float p0 = exp2f(st[mt][nt][0] * sc - mx[nt]);
            float p1 = exp2f(st[mt][nt][1] * sc - mx[nt]);
            float p2 = exp2f(st[mt][nt][2] * sc - mx[nt]);
            float p3 = exp2f(st[mt][nt][3] * sc - mx[nt]);
            s += (p0 + p1) + (p2 + p3);
            ppk[mt][nt][0] = (unsigned)f2b(p0) | ((unsigned)f2b(p1) << 16);
            ppk[mt][nt][1] = (unsigned)f2b(p2) | ((unsigned)f2b(p3) << 16);
        }
        s += __shfl_xor(s, 16);
        s += __shfl_xor(s, 32);
        rinv[nt] = 1.0f / s;
    }

    f32x4 ov[4][2] = {};
    int g = lane >> 4;
    int ls0 = (lane & 15) | ((g & 1) << 5);
    int ls1 = ls0 | 16;
    int hi = g >> 1;
#pragma unroll
    for (int kt = 0; kt < 4; ++kt) {
        bf16x8 bp[2];
#pragma unroll
        for (int nt = 0; nt < 2; ++nt) {
            unsigned a0 = (unsigned)__shfl((int)ppk[2 * kt    ][nt][0], ls0);
            unsigned b0 = (unsigned)__shfl((int)ppk[2 * kt + 1][nt][0], ls0);
            unsigned a1 = (unsigned)__shfl((int)ppk[2 * kt    ][nt][1], ls0);
            unsigned b1 = (unsigned)__shfl((int)ppk[2 * kt + 1][nt][1], ls0);
            unsigned a2 = (unsigned)__shfl((int)ppk[2 * kt    ][nt][0], ls1);
            unsigned b2 = (unsigned)__shfl((int)ppk[2 * kt + 1][nt][0], ls1);
            unsigned a3 = (unsigned)__shfl((int)ppk[2 * kt    ][nt][1], ls1);
            unsigned b3 = (unsigned)__shfl((int)ppk[2 * kt + 1][nt][1], ls1);
            union { unsigned u[4]; bf16x8 v; } pk;
            pk.u[0] = hi ? b0 : a0;
            pk.u[1] = hi ? b1 : a1;
            pk.u[2] = hi ? b2 : a2;
            pk.u[3] = hi ? b3 : a3;
            bp[nt] = pk.v;
        }
#pragma unroll
        for (int dt = 0; dt < 4; ++dt) {
            bf16x8 av = *(const bf16x8*)(Vt + (dt * 16 + (lane & 15)) * 144 + kt * 32 + (lane >> 4) * 8);
#pragma unroll
            for (int nt = 0; nt < 2; ++nt)
                ov[dt][nt] = __builtin_amdgcn_mfma_f32_16x16x32_bf16(av, bp[nt], ov[dt][nt], 0, 0, 0);
        }
    }

#pragma unroll
    for (int dt = 0; dt < 4; ++dt) {
        int d0 = dt * 16 + (lane >> 4) * 4;
#pragma unroll
        for (int nt = 0; nt < 2; ++nt) {
            int i = wv * 32 + nt * 16 + (lane & 15);
            size_t p = ((size_t)(b * 128 + sq)) * 128 + i;
            ushort4 o;
            o.x = f2b(ov[dt][nt][0] * rinv[nt]);
            o.y = f2b(ov[dt][nt][1] * rinv[nt]);
            o.z = f2b(ov[dt][nt][2] * rinv[nt]);
            o.w = f2b(ov[dt][nt][3] * rinv[nt]);
            *(ushort4*)(o2 + p * 512 + t * 64 + d0) = o;
        }
    }
}

extern "C" void kernel_launch(void* const* d_in, const int* in_sizes, int n_in,
                              void* d_out, int out_size, void* d_ws, size_t ws_size,
                              hipStream_t stream) {
    const float* x  = (const float*)d_in[0];
    const float* wq = (const float*)d_in[1];
    const float* wp = (const float*)d_in[2];
    float* out = (float*)d_out;
    char* ws = (char*)d_ws;
    unsigned short* wqb = (unsigned short*)(ws);
    unsigned short* wpb = (unsigned short*)(ws + ((size_t)2 << 20));
    unsigned short* xb  = (unsigned short*)(ws + ((size_t)4 << 20));
    unsigned short* o2  = (unsigned short*)(ws + ((size_t)68 << 20));
    unsigned short* qkv = (unsigned short*)(ws + ((size_t)132 << 20));

    cvt_w<<<1024, 256, 0, stream>>>(wq, wp, wqb, wpb);
    k0_tr<<<8192, 256, 0, stream>>>(x, xb);
    // pass 1 (axis = h)
    gemm8<0><<<12 * 512, 256, 0, stream>>>(wqb, xb, qkv, nullptr, nullptr, 12);
    attn_k<<<4096, 256, 0, stream>>>(qkv, o2);
    gemm8<1><<<4 * 512, 256, 0, stream>>>(wpb, o2, xb, nullptr, nullptr, 4);
    // pass 2 (axis = w)
    gemm8<0><<<12 * 512, 256, 0, stream>>>(wqb, xb, qkv, nullptr, nullptr, 12);
    attn_k<<<4096, 256, 0, stream>>>(qkv, o2);
    gemm8<2><<<4 * 512, 256, 0, stream>>>(wpb, o2, nullptr, x, out, 4);
}

// Round 14
// 570.143 us; speedup vs baseline: 1.3936x; 1.0496x over previous
//
#include <hip/hip_runtime.h>
#include <hip/hip_bf16.h>
#include <stdint.h>

#define B_ 4
#define S_ 128
#define CH 512

typedef __attribute__((ext_vector_type(8))) __bf16 bf16x8;
typedef __attribute__((ext_vector_type(4))) float  f32x4;
typedef __attribute__((ext_vector_type(16))) float f32x16;

__device__ __forceinline__ unsigned short f2b(float f) {
    union { float f; unsigned u; } v; v.f = f;
    unsigned r = v.u + 0x7FFFu + ((v.u >> 16) & 1u);
    return (unsigned short)(r >> 16);
}

#define GLD_LDS16(gp, lp) \
    __builtin_amdgcn_global_load_lds((const __attribute__((address_space(1))) void*)(gp), \
                                     (__attribute__((address_space(3))) void*)(lp), 16, 0, 0)

// ------- fused: x transpose/convert (bid<8192) + weight convert (bid>=8192) -------
__global__ __launch_bounds__(256) void k0_tr(const float* __restrict__ x,
                                             unsigned short* __restrict__ xb,
                                             const float* __restrict__ wq,
                                             const float* __restrict__ wp,
                                             unsigned short* __restrict__ wqb,
                                             unsigned short* __restrict__ wpb) {
    int bid = blockIdx.x;
    int tid = threadIdx.x;
    if (bid >= 8192) {
        int idx = ((bid - 8192) * 256 + tid) * 4;
        const float* s; unsigned short* d; int off;
        if (idx < 1536 * 512) { s = wq; d = wqb; off = idx; }
        else                  { s = wp; d = wpb; off = idx - 1536 * 512; }
        float4 v = *(const float4*)(s + off);
        ushort4 o; o.x = f2b(v.x); o.y = f2b(v.y); o.z = f2b(v.z); o.w = f2b(v.w);
        *(ushort4*)(d + off) = o;
        return;
    }
    __shared__ unsigned short t[64][72];
    int ct = bid & 7, wt = (bid >> 3) & 1, h = (bid >> 4) & 127, b = bid >> 11;
    int c0 = ct * 64, w0 = wt * 64;
    const float* xp = x + ((size_t)b * CH * S_ + h) * S_;
    int wl = (tid & 15) * 4;
#pragma unroll
    for (int it = 0; it < 4; ++it) {
        int c = it * 16 + (tid >> 4);
        float4 v = *(const float4*)(xp + (size_t)(c0 + c) * (S_ * S_) + w0 + wl);
        t[wl + 0][c] = f2b(v.x);
        t[wl + 1][c] = f2b(v.y);
        t[wl + 2][c] = f2b(v.z);
        t[wl + 3][c] = f2b(v.w);
    }
    __syncthreads();
#pragma unroll
    for (int it = 0; it < 2; ++it) {
        int w = it * 32 + (tid >> 3);
        int ce = (tid & 7) * 8;
        int4 v = *(const int4*)&t[w][ce];
        size_t p = (size_t)((b * 128 + w0 + w) * 128 + h);
        *(int4*)(xb + p * 512 + c0 + ce) = v;
    }
}

// ============ 256x256 GEMM (32x32x16), gray-code 4-phase, 3 barriers/K-tile ===
// Best-measured structure (r8): 8 waves (2M x 4N), BK=64, 128 KiB LDS.
// 3-bit XOR bank swizzle: ushort col ^= (row&7)<<3 on reads; staging keeps the
// LDS dest LINEAR (GLD constraint), global source col inverse-swizzled.
// Schedule: q0=(0,0) q1=(0,1) q2=(1,1) q3=(1,0); stages q0->A(j+1,1),
// q1->B(j+1,0), q2->A(j+2,0), q3->B(j+2,1)+vmcnt(4); barriers end-q1/q2/q3
// (region-lifetime proof in r7). GEMM plateau: 6 structures all land at
// ~165-170us for this shape (M=1536,K=512) -> shape-limited; do not restructure.
template<int EPI>
__global__ __launch_bounds__(512, 2) void gemm8(
    const unsigned short* __restrict__ A,
    const unsigned short* __restrict__ Bm,
    unsigned short* __restrict__ outb,
    const float* __restrict__ xres,
    float* __restrict__ outf,
    int Mtiles)
{
    __shared__ unsigned short lds[65536];   // A: [0,32768), B: [32768,65536)
    const int NT = 8;                       // 512 / BK(64)
    int nwg = gridDim.x;
    int wg = (blockIdx.x & 7) * (nwg >> 3) + (blockIdx.x >> 3);  // T1 XCD swizzle
    int mb = wg % Mtiles, nb = wg / Mtiles;
    int m0 = mb * 256, n0 = nb * 256;
    int tid = threadIdx.x, lane = tid & 63, wid = tid >> 6;
    int wm = wid >> 2, wn = wid & 3;

    f32x16 acc[4][2] = {};   // [mq*2+fr][nq]

    // fragment-read constants; swizzle: ushort col ^= (row&7)<<3, row = lane&31
    int l31  = lane & 31;
    int rsw  = (lane & 7) << 3;
    int cK[4];
#pragma unroll
    for (int ks = 0; ks < 4; ++ks)
        cK[ks] = (ks * 16 + (lane >> 5) * 8) ^ rsw;
    int arow0 = (wm * 64 + l31) * 64;      // + fr*32*64
    int brow  = (wn * 32 + l31) * 64;

    // staging: thread writes LDS row srow LINEARLY; source col inverse-swizzled
    int srow = tid >> 3;
    int scol = ((tid & 7) * 8) ^ ((srow & 7) << 3);
    const unsigned short* Ab0 = A  + (size_t)(m0 + srow) * 512 + scol;
    const unsigned short* Bb0 = Bm + (size_t)(n0 + (srow >> 5) * 64 + (srow & 31)) * 512 + scol;

#define STAGE_A(kt, reg) do {                                                  \
        unsigned short* lb_ = &lds[((((kt) & 1) * 2 + (reg)) * 8192)];         \
        const unsigned short* g_ = Ab0 + (size_t)(reg) * (64 * 512) + (kt) * 64;\
        GLD_LDS16(g_,             lb_ + wid * 512);                            \
        GLD_LDS16(g_ + 128 * 512, lb_ + 4096 + wid * 512);                     \
    } while (0)
#define STAGE_B(kt, reg) do {                                                  \
        unsigned short* lb_ = &lds[32768 + ((((kt) & 1) * 2 + (reg)) * 8192)]; \
        const unsigned short* g_ = Bb0 + (size_t)(reg) * (32 * 512) + (kt) * 64;\
        GLD_LDS16(g_,             lb_ + wid * 512);                            \
        GLD_LDS16(g_ + 128 * 512, lb_ + 4096 + wid * 512);                     \
    } while (0)

#define LOAD_AF(reg) do {                                                      \
        int abase_ = (db * 2 + (reg)) * 8192 + arow0;                          \
        _Pragma("unroll")                                                      \
        for (int fr = 0; fr < 2; ++fr)                                         \
            _Pragma("unroll")                                                  \
            for (int ks = 0; ks < 4; ++ks)                                     \
                af[fr][ks] = *(const bf16x8*)&lds[abase_ + fr * 2048 + cK[ks]];\
    } while (0)
#define LOAD_BQ(reg) do {                                                      \
        int bbase_ = 32768 + (db * 2 + (reg)) * 8192 + brow;                   \
        _Pragma("unroll")                                                      \
        for (int ks = 0; ks < 4; ++ks)                                         \
            bq[ks] = *(const bf16x8*)&lds[bbase_ + cK[ks]];                    \
    } while (0)
#define MFMA8(mq, nq)                                                          \
    __builtin_amdgcn_s_setprio(1);                                             \
    _Pragma("unroll")                                                          \
    for (int ks = 0; ks < 4; ++ks)                                             \
        _Pragma("unroll")                                                      \
        for (int fr = 0; fr < 2; ++fr)                                         \
            acc[(mq) * 2 + fr][nq] = __builtin_amdgcn_mfma_f32_32x32x16_bf16(  \
                af[fr][ks], bq[ks], acc[(mq) * 2 + fr][nq], 0, 0, 0);          \
    __builtin_amdgcn_s_setprio(0);

    // prologue: tile0 all 4 regions + next-tile carry {A(1,0), B(1,1)}
    STAGE_A(0, 0); STAGE_A(0, 1); STAGE_B(0, 0); STAGE_B(0, 1);
    STAGE_A(1, 0); STAGE_B(1, 1);
    asm volatile("s_waitcnt vmcnt(4)" ::: "memory");   // tile0's 8 loads done
    __builtin_amdgcn_s_barrier();

    for (int j = 0; j < NT; ++j) {
        const int db = j & 1;
        bf16x8 af[2][4], bq[4];
        // ---- q0: (mq0,nq0) ---- no entry barrier (overlaps prev q3 MFMA)
        LOAD_AF(0);
        LOAD_BQ(0);
        if (j + 1 < NT) STAGE_A(j + 1, 1);
        MFMA8(0, 0)
        // ---- q1: (mq0,nq1) ----
        LOAD_BQ(1);
        if (j + 1 < NT) STAGE_B(j + 1, 0);
        MFMA8(0, 1)
        __builtin_amdgcn_s_barrier();                  // B1
        // ---- q2: (mq1,nq1) ----
        LOAD_AF(1);
        LOAD_BQ(1);
        if (j + 2 < NT) STAGE_A(j + 2, 0);
        MFMA8(1, 1)
        __builtin_amdgcn_s_barrier();                  // B2
        // ---- q3: (mq1,nq0) ----
        LOAD_BQ(0);
        if (j + 2 < NT) STAGE_B(j + 2, 1);
        MFMA8(1, 0)
        if (j < NT - 2)       asm volatile("s_waitcnt vmcnt(4)" ::: "memory");
        else if (j == NT - 2) asm volatile("s_waitcnt vmcnt(0)" ::: "memory");
        __builtin_amdgcn_s_barrier();                  // B3
    }
#undef MFMA8
#undef LOAD_BQ
#undef LOAD_AF
#undef STAGE_A
#undef STAGE_B

#pragma unroll
    for (int mi2 = 0; mi2 < 4; ++mi2) {
#pragma unroll
        for (int qd = 0; qd < 4; ++qd) {
            int row0 = m0 + wm * 128 + mi2 * 32 + qd * 8 + ((lane >> 5) << 2);
#pragma unroll
            for (int nq = 0; nq < 2; ++nq) {
                int col = n0 + wn * 64 + nq * 32 + (lane & 31);
                int i = col & 127, sq = (col >> 7) & 127, bb = col >> 14;
                float a4[4];
#pragma unroll
                for (int r = 0; r < 4; ++r) a4[r] = acc[mi2][nq][qd * 4 + r];
                if (EPI == 0) {
                    int g = row0 >> 6, d0 = row0 & 63;
                    if (g < 16) {
                        size_t base = ((size_t)(g * 4 + bb) * 16384 + (size_t)sq * 128 + i) * 64 + d0;
                        ushort4 o;
                        o.x = f2b(a4[0]); o.y = f2b(a4[1]); o.z = f2b(a4[2]); o.w = f2b(a4[3]);
                        *(ushort4*)(outb + base) = o;
                    } else {
                        size_t base = ((size_t)(g * 4 + bb) * 8192 + (size_t)sq * 64 + d0) * 128 + i;
                        outb[base]       = f2b(a4[0]);
                        outb[base + 128] = f2b(a4[1]);
                        outb[base + 256] = f2b(a4[2]);
                        outb[base + 384] = f2b(a4[3]);
                    }
                } else if (EPI == 1) {
                    size_t p2 = ((size_t)bb * 128 + i) * 128 + sq;
                    ushort4 o;
                    o.x = f2b(a4[0]); o.y = f2b(a4[1]); o.z = f2b(a4[2]); o.w = f2b(a4[3]);
                    *(ushort4*)(outb + p2 * 512 + row0) = o;
                } else {
                    size_t base = (((size_t)bb * 512 + row0) * 128 + sq) * 128 + i;
#pragma unroll
                    for (int r = 0; r < 4; ++r) {
                        size_t a_ = base + (size_t)r * 16384;
                        outf[a_] = xres[a_] + a4[r];
                    }
                }
            }
        }
    }
}

// ---------------- attention: one block per (b, seq, head), 3 blocks/CU -------
// LDS 52.2 KB (pitches 68/136 ushorts: rows step 2 banks -> worst 2-way
// aliasing on b128 reads, free per m136) -> 3 blocks/CU for latency hiding.
__global__ __launch_bounds__(256) void attn_k(const unsigned short* __restrict__ qkv,
                                              unsigned short* __restrict__ o2) {
    __shared__ unsigned short Qs[128 * 68];
    __shared__ unsigned short Ks[128 * 68];
    __shared__ unsigned short Vt[64 * 136];
    int bid = blockIdx.x;
    int t = bid & 7, sq = (bid >> 3) & 127, b = bid >> 10;
    int tid = threadIdx.x, lane = tid & 63, wv = tid >> 6;
    const unsigned short* qg = qkv + ((size_t)(t * 4 + b) * 16384 + (size_t)sq * 128) * 64;
    const unsigned short* kg = qkv + ((size_t)((8 + t) * 4 + b) * 16384 + (size_t)sq * 128) * 64;
    const unsigned short* vg = qkv + ((size_t)((16 + t) * 4 + b) * 8192 + (size_t)sq * 64) * 128;
    {
        int r = tid >> 3, d0 = (tid & 7) * 8;
#pragma unroll
        for (int it = 0; it < 4; ++it) {
            *(int4*)(Qs + (it * 32 + r) * 68 + d0) = *(const int4*)(qg + (it * 32 + r) * 64 + d0);
            *(int4*)(Ks + (it * 32 + r) * 68 + d0) = *(const int4*)(kg + (it * 32 + r) * 64 + d0);
        }
        int r2 = tid >> 4, i0 = (tid & 15) * 8;
#pragma unroll
        for (int it = 0; it < 4; ++it)
            *(int4*)(Vt + (it * 16 + r2) * 136 + i0) = *(const int4*)(vg + (it * 16 + r2) * 128 + i0);
    }
    __syncthreads();

    f32x4 st[8][2] = {};
#pragma unroll
    for (int kk = 0; kk < 2; ++kk) {
        int ko = kk * 32 + (lane >> 4) * 8;
        bf16x8 bq[2];
#pragma unroll
        for (int nt = 0; nt < 2; ++nt)
            bq[nt] = *(const bf16x8*)(Qs + (wv * 32 + nt * 16 + (lane & 15)) * 68 + ko);
#pragma unroll
        for (int mt = 0; mt < 8; ++mt) {
            bf16x8 ak = *(const bf16x8*)(Ks + (mt * 16 + (lane & 15)) * 68 + ko);
#pragma unroll
            for (int nt = 0; nt < 2; ++nt)
                st[mt][nt] = __builtin_amdgcn_mfma_f32_16x16x32_bf16(ak, bq[nt], st[mt][nt], 0, 0, 0);
        }
    }

    const float sc = 0.125f * 1.44269504088896f;
    float mx[2], rinv[2];
    unsigned ppk[8][2][2];
#pragma unroll
    for (int nt = 0; nt < 2; ++nt) {
        float m = -3.0e38f;
#pragma unroll
        for (int mt = 0; mt < 8; ++mt)
#pragma unroll
            for (int r = 0; r < 4; ++r)
                m = fmaxf(m, st[mt][nt][r]);
        m = fmaxf(m, __shfl_xor(m, 16));
        m = fmaxf(m, __shfl_xor(m, 32));
        mx[nt] = m * sc;
    }
#pragma unroll
    for (int nt = 0; nt < 2; ++nt) {
        float s = 0.f;
#pragma unroll
        for (int mt = 0; mt < 8; ++mt) {
            float p0 = exp2f(st[mt][nt][0] * sc - mx[nt]);
            float p1 = exp2f(st[mt][nt][1] * sc - mx[nt]);
            float p2 = exp2f(st[mt][nt][2] * sc - mx[nt]);
            float p3 = exp2f(st[mt][nt][3] * sc - mx[nt]);
            s += (p0 + p1) + (p2 + p3);
            ppk[mt][nt][0] = (unsigned)f2b(p0) | ((unsigned)f2b(p1) << 16);
            ppk[mt][nt][1] = (unsigned)f2b(p2) | ((unsigned)f2b(p3) << 16);
        }
        s += __shfl_xor(s, 16);
        s += __shfl_xor(s, 32);
        rinv[nt] = 1.0f / s;
    }

    f32x4 ov[4][2] = {};
    int g = lane >> 4;
    int ls0 = (lane & 15) | ((g & 1) << 5);
    int ls1 = ls0 | 16;
    int hi = g >> 1;
#pragma unroll
    for (int kt = 0; kt < 4; ++kt) {
        bf16x8 bp[2];
#pragma unroll
        for (int nt = 0; nt < 2; ++nt) {
            unsigned a0 = (unsigned)__shfl((int)ppk[2 * kt    ][nt][0], ls0);
            unsigned b0 = (unsigned)__shfl((int)ppk[2 * kt + 1][nt][0], ls0);
            unsigned a1 = (unsigned)__shfl((int)ppk[2 * kt    ][nt][1], ls0);
            unsigned b1 = (unsigned)__shfl((int)ppk[2 * kt + 1][nt][1], ls0);
            unsigned a2 = (unsigned)__shfl((int)ppk[2 * kt    ][nt][0], ls1);
            unsigned b2 = (unsigned)__shfl((int)ppk[2 * kt + 1][nt][0], ls1);
            unsigned a3 = (unsigned)__shfl((int)ppk[2 * kt    ][nt][1], ls1);
            unsigned b3 = (unsigned)__shfl((int)ppk[2 * kt + 1][nt][1], ls1);
            union { unsigned u[4]; bf16x8 v; } pk;
            pk.u[0] = hi ? b0 : a0;
            pk.u[1] = hi ? b1 : a1;
            pk.u[2] = hi ? b2 : a2;
            pk.u[3] = hi ? b3 : a3;
            bp[nt] = pk.v;
        }
#pragma unroll
        for (int dt = 0; dt < 4; ++dt) {
            bf16x8 av = *(const bf16x8*)(Vt + (dt * 16 + (lane & 15)) * 136 + kt * 32 + (lane >> 4) * 8);
#pragma unroll
            for (int nt = 0; nt < 2; ++nt)
                ov[dt][nt] = __builtin_amdgcn_mfma_f32_16x16x32_bf16(av, bp[nt], ov[dt][nt], 0, 0, 0);
        }
    }

#pragma unroll
    for (int dt = 0; dt < 4; ++dt) {
        int d0 = dt * 16 + (lane >> 4) * 4;
#pragma unroll
        for (int nt = 0; nt < 2; ++nt) {
            int i = wv * 32 + nt * 16 + (lane & 15);
            size_t p = ((size_t)(b * 128 + sq)) * 128 + i;
            ushort4 o;
            o.x = f2b(ov[dt][nt][0] * rinv[nt]);
            o.y = f2b(ov[dt][nt][1] * rinv[nt]);
            o.z = f2b(ov[dt][nt][2] * rinv[nt]);
            o.w = f2b(ov[dt][nt][3] * rinv[nt]);
            *(ushort4*)(o2 + p * 512 + t * 64 + d0) = o;
        }
    }
}

extern "C" void kernel_launch(void* const* d_in, const int* in_sizes, int n_in,
                              void* d_out, int out_size, void* d_ws, size_t ws_size,
                              hipStream_t stream) {
    const float* x  = (const float*)d_in[0];
    const float* wq = (const float*)d_in[1];
    const float* wp = (const float*)d_in[2];
    float* out = (float*)d_out;
    char* ws = (char*)d_ws;
    unsigned short* wqb = (unsigned short*)(ws);
    unsigned short* wpb = (unsigned short*)(ws + ((size_t)2 << 20));
    unsigned short* xb  = (unsigned short*)(ws + ((size_t)4 << 20));
    unsigned short* o2  = (unsigned short*)(ws + ((size_t)68 << 20));
    unsigned short* qkv = (unsigned short*)(ws + ((size_t)132 << 20));

    k0_tr<<<9216, 256, 0, stream>>>(x, xb, wq, wp, wqb, wpb);
    // pass 1 (axis = h)
    gemm8<0><<<6 * 256, 512, 0, stream>>>(wqb, xb, qkv, nullptr, nullptr, 6);
    attn_k<<<4096, 256, 0, stream>>>(qkv, o2);
    gemm8<1><<<2 * 256, 512, 0, stream>>>(wpb, o2, xb, nullptr, nullptr, 2);
    // pass 2 (axis = w)
    gemm8<0><<<6 * 256, 512, 0, stream>>>(wqb, xb, qkv, nullptr, nullptr, 6);
    attn_k<<<4096, 256, 0, stream>>>(qkv, o2);
    gemm8<2><<<2 * 256, 512, 0, stream>>>(wpb, o2, nullptr, x, out, 2);
}